// Round 5
// baseline (732.793 us; speedup 1.0000x reference)
//
#include <hip/hip_runtime.h>
#include <stdint.h>
#include <stddef.h>

// CNNLSTM: embed -> conv1d(K=5) -> ReLU -> maxpool4 -> LSTM(T=1023,H=128) -> fc(2)
// Inputs: x int32; all float tensors float32. Output f32.
// Internals: bf16 MFMA for conv + input-projection GEMMs; f16 MFMA recurrence.

typedef __bf16 bf16;
typedef __bf16 bf16x8 __attribute__((ext_vector_type(8)));
typedef float  f32x4  __attribute__((ext_vector_type(4)));
typedef _Float16 f16;
typedef f16 f16x2 __attribute__((ext_vector_type(2)));
typedef f16 f16x4 __attribute__((ext_vector_type(4)));
typedef f16 f16x8 __attribute__((ext_vector_type(8)));

#define MFMA16(a, b, c)  __builtin_amdgcn_mfma_f32_16x16x32_bf16((a), (b), (c), 0, 0, 0)
#define MFMA16H(a, b, c) __builtin_amdgcn_mfma_f32_16x16x32_f16((a), (b), (c), 0, 0, 0)

// Barrier draining LDS (lgkm) but NOT in-flight global prefetch loads.
#define LGKM_BARRIER() asm volatile("s_waitcnt lgkmcnt(0)\ns_barrier" ::: "memory")

// ---------------- ws layout (bytes) ----------------
#define WS_BT     0               // conv weights repacked [64][640] bf16 =    81,920
#define WS_WIHB   81920           // w_ih bf16 [512][64]                  =    65,536
#define WS_POOLED 278528          // pooled bf16 [64][1024][64]           = 8,388,608
#define WS_EMB    8667136         // emb bf16 [20000][128]                = 5,120,000
#define WS_XG     8667136         // xgc f16 [64][128][128][4][8]         = 67,108,864
// (xgc overlaps emb_bf16: emb dead after conv_pool)

// ============ prep A: emb f32 -> bf16 ============
__global__ void emb_cvt_k(const float* __restrict__ emb, bf16* __restrict__ embb) {
    int g = blockIdx.x * 256 + threadIdx.x;
    f32x4 v = *(const f32x4*)(emb + g * 4);
    bf16* d = embb + g * 4;
    d[0] = (bf16)v[0]; d[1] = (bf16)v[1]; d[2] = (bf16)v[2]; d[3] = (bf16)v[3];
}

// ============ prep B: conv_w repack->bf16; w_ih->bf16 ============
__global__ void prep_small_k(const float* __restrict__ conv_w, bf16* __restrict__ bt,
                             const float* __restrict__ w_ih, bf16* __restrict__ w_ihb) {
    int g = blockIdx.x * 256 + threadIdx.x;
    if (g < 64 * 640) {
        int f = g / 640, kk = g - f * 640;
        int k = kk >> 7, e = kk & 127;
        bt[g] = (bf16)conv_w[(f * 128 + e) * 5 + k];
    } else {
        int h = g - 64 * 640;
        if (h < 512 * 64) w_ihb[h] = (bf16)w_ih[h];
    }
}

// ============ kernel 1: embed-gather + conv + ReLU + pool4 ============
__global__ __launch_bounds__(256, 2) void conv_pool_k(
    const int* __restrict__ x, const bf16* __restrict__ embb,
    const bf16* __restrict__ bt, const float* __restrict__ conv_b,
    bf16* __restrict__ pooled)
{
    __shared__ bf16 T[144 * 136];  // 136 = 128 + 8 pad
    const int b   = blockIdx.x >> 5;
    const int l0  = (blockIdx.x & 31) << 7;
    const int tid = threadIdx.x;
    const int ln  = tid & 63, w = tid >> 6;
    const int l15 = ln & 15, quad = ln >> 4;
    const int f   = w * 16 + l15;

    bf16x8 bfrag[20];
    #pragma unroll
    for (int kc = 0; kc < 20; ++kc) {
        uint4 v = *(const uint4*)(bt + f * 640 + kc * 32 + quad * 8);
        bfrag[kc] = __builtin_bit_cast(bf16x8, v);
    }
    const float cb = conv_b[f];

    #pragma unroll
    for (int p = 0; p < 9; ++p) {
        int r = p * 16 + (tid >> 4);
        int cg = tid & 15;
        int token = l0 + r; if (token > 4095) token = 4095;
        int idx = x[b * 4096 + token];
        uint4 v = *(const uint4*)(embb + idx * 128 + cg * 8);
        *(uint4*)(&T[r * 136 + cg * 8]) = v;
    }
    __syncthreads();

    f32x4 acc[8];
    #pragma unroll
    for (int tm = 0; tm < 8; ++tm) acc[tm] = (f32x4){0.f, 0.f, 0.f, 0.f};

    #pragma unroll
    for (int kc = 0; kc < 20; ++kc) {
        const int ktap = kc >> 2;
        const int ecol = (kc & 3) * 32 + quad * 8;
        #pragma unroll
        for (int tm = 0; tm < 8; ++tm) {
            int row = tm * 16 + l15 + ktap;
            bf16x8 a = *(const bf16x8*)(&T[row * 136 + ecol]);
            acc[tm] = MFMA16(a, bfrag[kc], acc[tm]);
        }
    }

    #pragma unroll
    for (int tm = 0; tm < 8; ++tm) {
        float mx = fmaxf(fmaxf(acc[tm][0], acc[tm][1]), fmaxf(acc[tm][2], acc[tm][3]));
        mx = fmaxf(mx + cb, 0.f);
        int t = (l0 >> 2) + tm * 4 + quad;
        if (t < 1023) pooled[(b * 1024 + t) * 64 + f] = (bf16)mx;
    }
}

// ============ kernel 2: xgc = pooled @ w_ih^T + (b_ih+b_hh), chunk-layout f16 ============
// xgc[b][c][unit][gate][j], t = c*8+j. LSTM lane reads 64 contiguous B/chunk.
__global__ __launch_bounds__(256, 2) void xg_gemm_k(
    const bf16* __restrict__ pooled, const bf16* __restrict__ w_ihb,
    const float* __restrict__ b_ih, const float* __restrict__ b_hh,
    f16* __restrict__ xg)
{
    __shared__ bf16 A[256 * 72];  // 72 = 64 + 8 pad
    const int m0  = blockIdx.x * 256;
    const int tid = threadIdx.x;
    const int ln  = tid & 63, w = tid >> 6;
    const int l15 = ln & 15, quad = ln >> 4;

    #pragma unroll
    for (int i = 0; i < 8; ++i) {
        int task = i * 256 + tid;
        int row = task >> 3, ch = task & 7;
        uint4 v = *(const uint4*)(pooled + (m0 + row) * 64 + ch * 8);
        *(uint4*)(&A[row * 72 + ch * 8]) = v;
    }
    __syncthreads();

    bf16x8 afrag[4][2];
    #pragma unroll
    for (int mt = 0; mt < 4; ++mt)
        #pragma unroll
        for (int kc = 0; kc < 2; ++kc)
            afrag[mt][kc] = *(const bf16x8*)(&A[((w * 4 + mt) * 16 + l15) * 72 + kc * 32 + quad * 8]);

    const int b_idx = m0 >> 10;
    const int tbase = m0 & 1023;

    for (int nt = 0; nt < 32; ++nt) {
        const int nn = nt * 16 + l15;
        uint4 v0 = *(const uint4*)(w_ihb + nn * 64 + quad * 8);
        uint4 v1 = *(const uint4*)(w_ihb + nn * 64 + 32 + quad * 8);
        bf16x8 bf0 = __builtin_bit_cast(bf16x8, v0);
        bf16x8 bf1 = __builtin_bit_cast(bf16x8, v1);
        const float bias = b_ih[nn] + b_hh[nn];
        const int unit = nn & 127, gate = nn >> 7;
        #pragma unroll
        for (int mt = 0; mt < 4; ++mt) {
            f32x4 acc = (f32x4){0.f, 0.f, 0.f, 0.f};
            acc = MFMA16(afrag[mt][0], bf0, acc);
            acc = MFMA16(afrag[mt][1], bf1, acc);
            int t0 = tbase + (w * 4 + mt) * 16 + quad * 4;   // t0 % 4 == 0
            f16x4 sv = {(f16)(acc[0] + bias), (f16)(acc[1] + bias),
                        (f16)(acc[2] + bias), (f16)(acc[3] + bias)};
            size_t off = (((size_t)(b_idx * 128 + (t0 >> 3)) * 128 + unit) * 4 + gate) * 8 + (t0 & 7);
            *(f16x4*)(xg + off) = sv;   // 8B store, (t0&7) in {0,4}
        }
    }
}

// ============ kernel 3: LSTM recurrence (f16 MFMA) + fc head ============
// 32 WGs x 256 threads (4 waves, 1 wave/EU exclusive). WG handles 2 batches.
// Wave w owns units w*32..w*32+31, all 4 gates: 8 acc-tiles (4 gates x 2
// unit-groups of 16) x 4 K-chunks = 32 mfma_f32_16x16x32_f16 per step as 8
// independent 4-deep chains -> issue-bound on an exclusive SIMD (~154cyc).
// B cols = 2 batches x 8 replicas (bb=l15>>3, c=l15&7). Lane runs exactly ONE
// act/cell chain: unit u = w*32 + (c>>2)*16 + quad*4 + (c&3), batch bb
// (bijective lane<->(u,bb)); acc pick: cndmask tree (rule #20: no runtime
// vector idx). R2 lesson: step latency (1088cyc) was wave-count-dominated
// (8-wave barrier skew + 32 queued ds_read_b128); 4 waves halves both.
// R3/R4 containers died with no diagnostics on this same decomposition;
// suspected compile-time blowup of the 127-trip loop with a 256-MFMA body.
// Hedge: "#pragma unroll 1" on the chunk loop + compact kc-loops (same
// semantics, one-chunk scheduled region).
__device__ inline float sigm_(float v) {
    return __builtin_amdgcn_rcpf(1.f + __builtin_amdgcn_exp2f(-1.4426950408889634f * v));
}
__device__ inline float tanh_(float v) {
    return 1.f - 2.f * __builtin_amdgcn_rcpf(1.f + __builtin_amdgcn_exp2f(2.8853901817779268f * v));
}

__global__ __launch_bounds__(256, 1) __attribute__((amdgpu_waves_per_eu(1, 1)))
void lstm_fc_k(
    const f16* __restrict__ xgc, const float* __restrict__ w_hh,
    const float* __restrict__ fc_w, const float* __restrict__ fc_b,
    float* __restrict__ out)
{
    __shared__ __align__(16) f16 hbuf[2][2][144];   // [p][bb][144]; 288B batch stride
    const int b0   = blockIdx.x << 1;
    const int t    = threadIdx.x;     // 0..255
    const int w    = t >> 6;          // wave 0..3 -> units w*32..w*32+31
    const int ln   = t & 63;
    const int l15  = ln & 15, quad = ln >> 4;
    const int bb   = l15 >> 3;        // batch sub 0..1
    const int c    = l15 & 7;         // replica 0..7
    const int ug   = c >> 2;          // unit-group 0..1
    const int u    = w * 32 + ug * 16 + quad * 4 + (c & 3);  // unit of this lane

    // ---- A fragments: wa[g][ugi][kc], lane holds
    // W_hh[g*128 + w*32 + ugi*16 + l15][kc*32 + quad*8 + j], j=0..7
    f16x8 wa[4][2][4];
    #pragma unroll
    for (int g = 0; g < 4; ++g)
        #pragma unroll
        for (int ugi = 0; ugi < 2; ++ugi)
            #pragma unroll
            for (int kc = 0; kc < 4; ++kc) {
                const float* wr = w_hh + (size_t)(g * 128 + w * 32 + ugi * 16 + l15) * 128
                                + kc * 32 + quad * 8;
                f32x4 v0 = *(const f32x4*)(wr);
                f32x4 v1 = *(const f32x4*)(wr + 4);
                wa[g][ugi][kc] = (f16x8){(f16)v0[0], (f16)v0[1], (f16)v0[2], (f16)v0[3],
                                         (f16)v1[0], (f16)v1[1], (f16)v1[2], (f16)v1[3]};
            }
    #pragma unroll
    for (int g = 0; g < 4; ++g)
        #pragma unroll
        for (int ugi = 0; ugi < 2; ++ugi)
            #pragma unroll
            for (int kc = 0; kc < 4; ++kc) {
                uint4 r = __builtin_bit_cast(uint4, wa[g][ugi][kc]);
                asm volatile("" : "+v"(r.x), "+v"(r.y), "+v"(r.z), "+v"(r.w));  // pin
                wa[g][ugi][kc] = __builtin_bit_cast(f16x8, r);
            }

    // xq for this lane's (batch, unit): xgc[b0+bb][ch][u][g][j]
    const f16* xb = xgc + (size_t)(b0 + bb) * 524288 + (size_t)u * 32;
    f16x8 xq0 = *(const f16x8*)(xb);
    f16x8 xq1 = *(const f16x8*)(xb + 8);
    f16x8 xq2 = *(const f16x8*)(xb + 16);
    f16x8 xq3 = *(const f16x8*)(xb + 24);
    f16x8 nx0, nx1, nx2, nx3;

    // B-frag read bases (p=0/1) and h write addrs (step p writes hbuf[p^1])
    const char* rb0 = (const char*)hbuf + bb * 288 + quad * 16;
    const char* rb1 = rb0 + 576;
    f16* wb0 = (f16*)((char*)hbuf + 576 + bb * 288 + u * 2);  // p=0 -> hbuf[1]
    f16* wb1 = (f16*)((char*)hbuf +       bb * 288 + u * 2);  // p=1 -> hbuf[0]

    if (t < 144) ((uint32_t*)hbuf)[t] = 0u;   // zero hbuf[0] (576B)
    float cst = 0.f;
    LGKM_BARRIER();

    const f32x4 zf = (f32x4){0.f, 0.f, 0.f, 0.f};

    auto step = [&](int j, int p) {
        const char* rb = p ? rb1 : rb0;
        f16x8 hb[4];
        #pragma unroll
        for (int kc = 0; kc < 4; ++kc) hb[kc] = *(const f16x8*)(rb + kc * 64);
        // 8 independent 4-deep MFMA chains (compiler interleaves; dep hidden)
        f32x4 acc[4][2];
        #pragma unroll
        for (int g = 0; g < 4; ++g)
            #pragma unroll
            for (int ugi = 0; ugi < 2; ++ugi) {
                f32x4 a = MFMA16H(wa[g][ugi][0], hb[0], zf);
                a = MFMA16H(wa[g][ugi][1], hb[1], a);
                a = MFMA16H(wa[g][ugi][2], hb[2], a);
                a = MFMA16H(wa[g][ugi][3], hb[3], a);
                acc[g][ugi] = a;
            }
        // extract this lane's preact per gate: reg c&3, tile c>>2 (cndmask tree)
        float pre[4];
        #pragma unroll
        for (int g = 0; g < 4; ++g) {
            float e0a = (c & 1) ? acc[g][0][1] : acc[g][0][0];
            float e0b = (c & 1) ? acc[g][0][3] : acc[g][0][2];
            float e0  = (c & 2) ? e0b : e0a;
            float e1a = (c & 1) ? acc[g][1][1] : acc[g][1][0];
            float e1b = (c & 1) ? acc[g][1][3] : acc[g][1][2];
            float e1  = (c & 2) ? e1b : e1a;
            pre[g] = ug ? e1 : e0;
        }
        float ig = sigm_(pre[0] + (float)xq0[j]);
        float fg = sigm_(pre[1] + (float)xq1[j]);
        float gg = tanh_(pre[2] + (float)xq2[j]);
        float og = sigm_(pre[3] + (float)xq3[j]);
        cst = fg * cst + ig * gg;
        float hn = og * tanh_(cst);
        *(p ? wb1 : wb0) = (f16)hn;
        LGKM_BARRIER();
    };

    #pragma unroll 1
    for (int ch = 0; ch < 127; ++ch) {
        // prefetch next chunk (vmcnt: not drained by the lgkm barrier)
        const f16* nb = xb + (size_t)(ch + 1) * 4096;
        nx0 = *(const f16x8*)(nb);
        nx1 = *(const f16x8*)(nb + 8);
        nx2 = *(const f16x8*)(nb + 16);
        nx3 = *(const f16x8*)(nb + 24);
        #pragma unroll
        for (int j = 0; j < 8; ++j) step(j, j & 1);
        xq0 = nx0; xq1 = nx1; xq2 = nx2; xq3 = nx3;
    }
    #pragma unroll
    for (int j = 0; j < 7; ++j) step(j, j & 1);   // steps 1016..1022; final h -> hbuf[1]

    // fc: out[b0+bbf][c2] = h_T . fc_w[c2] + fc_b[c2]   (h_T in hbuf[1])
    // wave w handles combo (bbf = w>>1, c2 = w&1); lane sums 2 units.
    {
        int bbf = w >> 1, c2 = w & 1;
        const f16* hrow = (const f16*)((const char*)hbuf + 576 + bbf * 288);
        float pr = (float)hrow[ln] * fc_w[c2 * 128 + ln]
                 + (float)hrow[64 + ln] * fc_w[c2 * 128 + 64 + ln];
        #pragma unroll
        for (int off = 32; off > 0; off >>= 1) pr += __shfl_down(pr, off, 64);
        if (ln == 0) out[(b0 + bbf) * 2 + c2] = pr + fc_b[c2];
    }
}

// ============================ launcher ============================
extern "C" void kernel_launch(void* const* d_in, const int* in_sizes, int n_in,
                              void* d_out, int out_size, void* d_ws, size_t ws_size,
                              hipStream_t stream) {
    const int*   x      = (const int*)d_in[0];
    const float* emb    = (const float*)d_in[1];
    const float* conv_w = (const float*)d_in[2];
    const float* conv_b = (const float*)d_in[3];
    const float* w_ih   = (const float*)d_in[4];
    const float* w_hh   = (const float*)d_in[5];
    const float* b_ih   = (const float*)d_in[6];
    const float* b_hh   = (const float*)d_in[7];
    const float* fc_w   = (const float*)d_in[8];
    const float* fc_b   = (const float*)d_in[9];
    float* out = (float*)d_out;

    char* ws = (char*)d_ws;
    bf16* bt     = (bf16*)(ws + WS_BT);
    bf16* w_ihb  = (bf16*)(ws + WS_WIHB);
    bf16* pooled = (bf16*)(ws + WS_POOLED);
    bf16* embb   = (bf16*)(ws + WS_EMB);
    f16*  xg     = (f16*)(ws + WS_XG);   // overlaps embb (emb dead after conv_pool)

    emb_cvt_k<<<2500, 256, 0, stream>>>(emb, embb);
    prep_small_k<<<288, 256, 0, stream>>>(conv_w, bt, w_ih, w_ihb);
    conv_pool_k<<<2048, 256, 0, stream>>>(x, embb, bt, conv_b, pooled);
    xg_gemm_k<<<256, 256, 0, stream>>>(pooled, w_ihb, b_ih, b_hh, xg);
    lstm_fc_k<<<32, 256, 0, stream>>>(xg, w_hh, fc_w, fc_b, out);
}